// Round 13
// baseline (141.066 us; speedup 1.0000x reference)
//
#include <hip/hip_runtime.h>
#include <hip/hip_bf16.h>
#include <math.h>

// ProxyGML: B=1024, DIM=512, C=1000, N=8
#define PB   1024
#define PDIM 512
#define PC   1000
#define PN   8
#define PCN  8000
#define PTOPK 400
#define NONPOS_K 392
#define NBIN 1024
#define CANDMAX 1024

typedef __bf16 bf16x8 __attribute__((ext_vector_type(8)));
typedef __bf16 bf16x4 __attribute__((ext_vector_type(4)));
typedef float  f32x4  __attribute__((ext_vector_type(4)));

__device__ static inline void async_load16(const __bf16* g, __bf16* l) {
    __builtin_amdgcn_global_load_lds(
        (const __attribute__((address_space(1))) void*)g,
        (__attribute__((address_space(3))) void*)l,
        16, 0, 0);
}

// ----------------------------------------------------------------- pre ----
// b<512: x->bf16. 512..767: P column-ssq partials. 768+: zero esum/diag and
// ccls pad rows (classes 1000..1023).
__global__ __launch_bounds__(256) void k_pre(const float* __restrict__ x,
                                             const float* __restrict__ P,
                                             __bf16* __restrict__ xb,
                                             float* __restrict__ ssqp,
                                             float* __restrict__ esd,
                                             float* __restrict__ padf,
                                             float* __restrict__ acc) {
    int b = blockIdx.x, tid = threadIdx.x;
    if (b == 0 && tid < 8) acc[tid] = 0.f;
    if (b < 512) {
        int i = b * 256 + tid;
        float4 v = ((const float4*)x)[i];
        bf16x4 o;
        o[0] = (__bf16)v.x; o[1] = (__bf16)v.y; o[2] = (__bf16)v.z; o[3] = (__bf16)v.w;
        ((bf16x4*)xb)[i] = o;
    } else if (b < 768) {
        int idx = b - 512;              // 0..255
        int slice = idx & 7, jb = idx >> 3;
        int j = jb * 256 + tid;
        if (j < PCN) {
            const float* p = P + (size_t)(slice * 64) * PCN + j;
            float ss = 0.f;
#pragma unroll 8
            for (int r = 0; r < 64; ++r) {
                float v = p[(size_t)r * PCN];
                ss = fmaf(v, v, ss);
            }
            ssqp[slice * PCN + j] = ss;
        }
    } else {
        int i = (b - 768) * 256 + tid;  // 0..22271
        if (i < 16000) esd[i] = 0.f;
        else if (i < 16000 + 6144) padf[i - 16000] = 0.f;  // 24x512 bf16 pad
    }
}

// ---------------- P (512x8000) -> Pt bf16 (8000x512) + fused ccls ---------
__global__ __launch_bounds__(256) void k_tpose(const float* __restrict__ P,
                                               const float* __restrict__ ssqp,
                                               __bf16* __restrict__ Pt,
                                               __bf16* __restrict__ ccls) {
    __shared__ float t[64][65];
    __shared__ float sinv[64];
    int tid = threadIdx.x;
    int tx = tid & 63, ty = tid >> 6;
    int j0 = blockIdx.x * 64, d0 = blockIdx.y * 64;
    if (tid < 64) {
        float sq = 0.f;
#pragma unroll
        for (int p2 = 0; p2 < 8; ++p2) sq += ssqp[p2 * PCN + j0 + tid];
        sinv[tid] = 1.0f / fmaxf(sqrtf(sq), 1e-12f);
    }
#pragma unroll
    for (int r = 0; r < 16; ++r) {
        int d = d0 + ty * 16 + r;
        t[ty * 16 + r][tx] = P[(size_t)d * PCN + j0 + tx];
    }
    __syncthreads();
    float cs0 = 0.f, cs1 = 0.f;
#pragma unroll
    for (int r = 0; r < 16; ++r) {
        int jl = ty * 16 + r;
        float val = t[tx][jl] * sinv[jl];
        Pt[(size_t)(j0 + jl) * PDIM + d0 + tx] = (__bf16)val;
        if (r < 8) cs0 += val; else cs1 += val;
    }
    int c0 = (j0 >> 3) + ty * 2;           // 16 j's = 2 whole classes
    ccls[(size_t)c0 * PDIM + d0 + tx] = (__bf16)cs0;
    ccls[(size_t)(c0 + 1) * PDIM + d0 + tx] = (__bf16)cs1;
}

// -------------- pair-fused GEMM: block (jt,t) shares the Pt tile ----------
// sim[m=t-tile][j=jt-tile] = xb · Pt^T   and
// clog[j=jt-tile][c=t-tile] = Pt · ccls^T -> esum/diag epilogue.
// XCD-locality swizzle: XCD x (= id%8 dispatch heuristic) owns jt in
// [8x, 8x+8) so its L2 holds 8 Pt tiles instead of sweeping all 63.
__global__ __launch_bounds__(256, 2) void k_gemms(const __bf16* __restrict__ xb,
                                                  const __bf16* __restrict__ Pt,
                                                  const __bf16* __restrict__ ccls,
                                                  __bf16* __restrict__ simb,
                                                  float* __restrict__ esum,
                                                  float* __restrict__ diag) {
    __shared__ __bf16 Xs[2][128 * 32];
    __shared__ __bf16 Ps[2][128 * 32];
    __shared__ __bf16 Cs[2][128 * 32];
    int tid = threadIdx.x;
    int w = tid >> 6, lane = tid & 63;
    int wr = w >> 1, wc = w & 1;
    int quad = lane >> 4, l15 = lane & 15;
    int id = blockIdx.x;                   // 512 blocks
    int xcd = id & 7, q = id >> 3;         // q in [0,64)
    int jt = xcd * 8 + (q & 7);            // [8*xcd, 8*xcd+8)
    int t  = q >> 3;                       // [0,8)
    if (jt >= 63) return;                  // 8 dummy blocks
    int m0 = t * 128;                      // xb rows / ccls rows (exact)
    int n0 = jt * 128;                     // Pt rows (guard 8000)

    f32x4 accS[4][4] = {};                 // sim
    f32x4 accC[4][4] = {};                 // clog

#define STAGE3(buf, k0) {                                                     \
    _Pragma("unroll")                                                         \
    for (int pass = 0; pass < 2; ++pass) {                                    \
        int cc_ = pass * 256 + w * 64 + lane;                                 \
        int row_ = cc_ >> 2, ko_ = (cc_ & 3) * 8;                             \
        async_load16(xb + (size_t)(m0 + row_) * PDIM + (k0) + ko_,            \
                     &Xs[buf][cc_ * 8]);                                      \
        int prow = n0 + row_; if (prow > PCN - 1) prow = PCN - 1;             \
        async_load16(Pt + (size_t)prow * PDIM + (k0) + ko_,                   \
                     &Ps[buf][cc_ * 8]);                                      \
        async_load16(ccls + (size_t)(m0 + row_) * PDIM + (k0) + ko_,          \
                     &Cs[buf][cc_ * 8]);                                      \
    } }

    STAGE3(0, 0)
    for (int it = 0; it < 16; ++it) {
        int cur = it & 1;
        __syncthreads();
        if (it < 15) STAGE3(cur ^ 1, (it + 1) * 32)
        bf16x8 xa[4], pb[4], pa[4], cb[4];
#pragma unroll
        for (int i = 0; i < 4; ++i) {
            xa[i] = *(const bf16x8*)&Xs[cur][(wr * 64 + i * 16 + l15) * 32 + quad * 8];
            pb[i] = *(const bf16x8*)&Ps[cur][(wc * 64 + i * 16 + l15) * 32 + quad * 8];
            pa[i] = *(const bf16x8*)&Ps[cur][(wr * 64 + i * 16 + l15) * 32 + quad * 8];
            cb[i] = *(const bf16x8*)&Cs[cur][(wc * 64 + i * 16 + l15) * 32 + quad * 8];
        }
#pragma unroll
        for (int i = 0; i < 4; ++i)
#pragma unroll
            for (int j = 0; j < 4; ++j) {
                accS[i][j] = __builtin_amdgcn_mfma_f32_16x16x32_bf16(
                    xa[i], pb[j], accS[i][j], 0, 0, 0);
                accC[i][j] = __builtin_amdgcn_mfma_f32_16x16x32_bf16(
                    pa[i], cb[j], accC[i][j], 0, 0, 0);
            }
    }
#undef STAGE3

    // epilogue 1: sim store (rows m0+.., cols n0+.. over CN)
#pragma unroll
    for (int i = 0; i < 4; ++i) {
        int r0 = m0 + wr * 64 + i * 16 + quad * 4;
#pragma unroll
        for (int j = 0; j < 4; ++j) {
            int cc = n0 + wc * 64 + j * 16 + l15;
            if (cc < PCN) {
#pragma unroll
                for (int r = 0; r < 4; ++r)
                    simb[(size_t)(r0 + r) * PCN + cc] = (__bf16)accS[i][j][r];
            }
        }
    }
    // epilogue 2: clog -> esum/diag (rows n0+.. over CN, cols m0+.. over C)
#pragma unroll
    for (int i = 0; i < 4; ++i) {
        int r0 = n0 + wr * 64 + i * 16 + quad * 4;
        float psum[4] = {0.f, 0.f, 0.f, 0.f};
#pragma unroll
        for (int j = 0; j < 4; ++j) {
            int cc = m0 + wc * 64 + j * 16 + l15;
            bool cvalid = (cc < PC);
#pragma unroll
            for (int r = 0; r < 4; ++r) {
                float v = accC[i][j][r];
                psum[r] += cvalid ? expf(v) : 0.f;
                int rr = r0 + r;
                if (cvalid && rr < PCN && cc == (rr >> 3)) diag[rr] = v;
            }
        }
#pragma unroll
        for (int off = 1; off < 16; off <<= 1)
#pragma unroll
            for (int r = 0; r < 4; ++r)
                psum[r] += __shfl_xor(psum[r], off, 64);
        if (l15 == 0) {
#pragma unroll
            for (int r = 0; r < 4; ++r) {
                int rr = r0 + r;
                if (rr < PCN) atomicAdd(&esum[rr], psum[r]);
            }
        }
    }
}

// ------------------------------------------------------------- row loss ---
// Register-resident bf16 row; 1024-bin histogram select for tau; ties
// resolved by index order via parallel class-order prefix scan.
__global__ __launch_bounds__(256) void k_rowloss(const __bf16* __restrict__ sim,
                                                 const int* __restrict__ target,
                                                 float* __restrict__ acc) {
    __shared__ unsigned hist[NBIN];
    __shared__ float redf[8];
    __shared__ unsigned wtot[4];
    __shared__ float cand[CANDMAX];
    __shared__ unsigned candn;
    __shared__ int s_bin, s_A;
    __shared__ float s_tau;
    __shared__ int s_gt, s_eq;
    __shared__ float s_et;

    int b = blockIdx.x, tid = threadIdx.x;
    int lane = tid & 63, wv = tid >> 6;
    const bf16x8* row8 = (const bf16x8*)(sim + (size_t)b * PCN);
    int targ = target[b];

#pragma unroll
    for (int k = 0; k < 4; ++k) hist[tid + 256 * k] = 0u;
    if (tid == 0) candn = 0u;

    float pv[4][8];
    float lmn = INFINITY, lmx = -INFINITY;
#pragma unroll
    for (int k = 0; k < 4; ++k) {
        int c = tid + 256 * k;
        if (c < PC) {
            bf16x8 vv = row8[c];
#pragma unroll
            for (int n = 0; n < 8; ++n) pv[k][n] = (float)vv[n];
            if (c != targ) {
#pragma unroll
                for (int n = 0; n < 8; ++n) {
                    lmn = fminf(lmn, pv[k][n]);
                    lmx = fmaxf(lmx, pv[k][n]);
                }
            }
        } else {
#pragma unroll
            for (int n = 0; n < 8; ++n) pv[k][n] = 0.f;
        }
    }
    for (int off = 32; off; off >>= 1) {
        lmn = fminf(lmn, __shfl_down(lmn, off, 64));
        lmx = fmaxf(lmx, __shfl_down(lmx, off, 64));
    }
    if (lane == 0) { redf[wv] = lmn; redf[4 + wv] = lmx; }
    __syncthreads();
    float lo = fminf(fminf(redf[0], redf[1]), fminf(redf[2], redf[3]));
    float hi = fmaxf(fmaxf(redf[4], redf[5]), fmaxf(redf[6], redf[7]));
    float range = hi - lo;
    float scale = (range > 0.f) ? (float)NBIN / range : 0.f;

#pragma unroll
    for (int k = 0; k < 4; ++k) {
        int c = tid + 256 * k;
        if (c < PC && c != targ) {
#pragma unroll
            for (int n = 0; n < 8; ++n) {
                int bin = (int)((pv[k][n] - lo) * scale);
                bin = bin < 0 ? 0 : (bin > NBIN - 1 ? NBIN - 1 : bin);
                atomicAdd(&hist[bin], 1u);
            }
        }
    }
    __syncthreads();

    // suffix scan over 1024 bins
    int b0 = tid * 4;
    unsigned h0 = hist[b0], h1 = hist[b0 + 1], h2 = hist[b0 + 2], h3 = hist[b0 + 3];
    unsigned l3 = h3, l2 = h2 + l3, l1 = h1 + l2, l0 = h0 + l1;
    unsigned T = l0;
#pragma unroll
    for (int step = 1; step < 64; step <<= 1) {
        unsigned u = __shfl_down(T, step, 64);
        if (lane + step < 64) T += u;
    }
    if (lane == 0) wtot[wv] = T;
    __syncthreads();
    unsigned tail = 0;
#pragma unroll
    for (int w2 = 0; w2 < 4; ++w2) if (w2 > wv) tail += wtot[w2];
    unsigned E = T - l0 + tail;
    {
        unsigned sfx[4] = {l0 + E, l1 + E, l2 + E, l3 + E};
        unsigned nxt[4] = {l1 + E, l2 + E, l3 + E, E};
#pragma unroll
        for (int i = 0; i < 4; ++i)
            if (sfx[i] >= NONPOS_K && nxt[i] < NONPOS_K) {
                s_bin = b0 + i;
                s_A = (int)nxt[i];
            }
    }
    __syncthreads();
    int tbin = s_bin, A = s_A;

    // collect candidates in tau's bin
#pragma unroll
    for (int k = 0; k < 4; ++k) {
        int c = tid + 256 * k;
        if (c < PC && c != targ) {
#pragma unroll
            for (int n = 0; n < 8; ++n) {
                int bin = (int)((pv[k][n] - lo) * scale);
                bin = bin < 0 ? 0 : (bin > NBIN - 1 ? NBIN - 1 : bin);
                if (bin == tbin) {
                    unsigned idx = atomicAdd(&candn, 1u);
                    if (idx < CANDMAX) cand[idx] = pv[k][n];
                }
            }
        }
    }
    __syncthreads();
    int m = (int)candn; if (m > CANDMAX) m = CANDMAX;
    int rank = NONPOS_K - A;
    for (int ci = tid; ci < m; ci += 256) {
        float val = cand[ci];
        int g = 0, e = 0;
        for (int i = 0; i < m; ++i) {
            g += cand[i] > val;
            e += cand[i] == val;
        }
        if (g < rank && rank <= g + e) { s_tau = val; s_gt = g; s_eq = e; }
    }
    __syncthreads();
    float tau = s_tau;
    int cgt = A + s_gt, ceq = s_eq;
    int rem = NONPOS_K - cgt;              // ties to include, by index order
    bool all_eq = (rem >= ceq);

    // parallel tie offsets in class-index order
    int offs[4] = {0, 0, 0, 0};
    if (!all_eq) {
        unsigned chunk_base = 0;
#pragma unroll
        for (int k = 0; k < 4; ++k) {
            int c = tid + 256 * k;
            unsigned tn = 0;
            if (c < PC && c != targ) {
#pragma unroll
                for (int n = 0; n < 8; ++n) tn += (pv[k][n] == tau) ? 1u : 0u;
            }
            unsigned inc = tn;                       // inclusive wave scan
#pragma unroll
            for (int step = 1; step < 64; step <<= 1) {
                unsigned u = __shfl_up(inc, step, 64);
                if (lane >= step) inc += u;
            }
            __syncthreads();
            if (lane == 63) wtot[wv] = inc;
            __syncthreads();
            unsigned base = 0;
#pragma unroll
            for (int w2 = 0; w2 < 4; ++w2) if (w2 < wv) base += wtot[w2];
            offs[k] = (int)(chunk_base + base + inc - tn);
            chunk_base += wtot[0] + wtot[1] + wtot[2] + wtot[3];
        }
    }

    // logits -> exp -> loss
    float psum = 0.f;
#pragma unroll
    for (int k = 0; k < 4; ++k) {
        int c = tid + 256 * k;
        if (c >= PC) continue;
        float lg = 0.f;
        if (c == targ) {
#pragma unroll
            for (int n = 0; n < 8; ++n) lg += pv[k][n];
        } else {
#pragma unroll
            for (int n = 0; n < 8; ++n) {
                float v = pv[k][n];
                bool sel = v > tau;
                if (!sel && v == tau) {
                    if (all_eq) sel = true;
                    else { sel = (offs[k] < rem); offs[k]++; }
                }
                if (sel) lg += v;
            }
        }
        float e = (lg != 0.0f) ? expf(lg) : 0.0f;
        psum += e;
        if (c == targ) s_et = e;
    }
    for (int off = 32; off; off >>= 1) psum += __shfl_down(psum, off, 64);
    if (lane == 0) redf[wv] = psum;
    __syncthreads();
    if (tid == 0) {
        float denom = 1e-8f + redf[0] + redf[1] + redf[2] + redf[3];
        atomicAdd(acc, -logf(s_et / denom + 1e-20f));
    }
}

// --------------------------------------------------------------- final ----
__global__ __launch_bounds__(256) void k_final(const float* __restrict__ esum,
                                               const float* __restrict__ diag,
                                               const float* __restrict__ acc,
                                               float* __restrict__ out) {
    __shared__ float redf[4];
    int tid = threadIdx.x, lane = tid & 63, wv = tid >> 6;
    float s = 0.f;
    for (int j = tid; j < PCN; j += 256)
        s += logf(esum[j]) - diag[j];
    for (int off = 32; off; off >>= 1) s += __shfl_down(s, off, 64);
    if (lane == 0) redf[wv] = s;
    __syncthreads();
    if (tid == 0) {
        float rg = (redf[0] + redf[1] + redf[2] + redf[3]) * (1.0f / PCN);
        float lc = acc[0] * (1.0f / PB);
        out[0] = lc + 0.3f * rg;
        out[1] = lc;
    }
}

// ---------------------------------------------------------------------------
extern "C" void kernel_launch(void* const* d_in, const int* in_sizes, int n_in,
                              void* d_out, int out_size, void* d_ws, size_t ws_size,
                              hipStream_t stream) {
    const float* x       = (const float*)d_in[0];   // (1024, 512)
    const float* proxies = (const float*)d_in[1];   // (512, 8000)
    const int*   target  = (const int*)d_in[2];     // (1024,)
    float* out = (float*)d_out;
    float* ws  = (float*)d_ws;

    // workspace layout (float offsets) — spans verified:
    //   acc    [0,      64)
    //   ssqp   [64,     64064)     8x8000 f32
    //   esum   [64064,  72064)     8000 f32
    //   diag   [72064,  80064)     8000 f32
    //   xb     [80064,  342208)    1024x512 bf16 = 262144 f32
    //   cclsb  [342208, 604352)    1024x512 bf16 = 262144 f32
    //   Pt     [604352, 2652352)   8000x512 bf16 = 2048000 f32
    //   simb   [2652352,6748352)   1024x8000 bf16 = 4096000 f32
    float*  acc   = ws;
    float*  ssqp  = ws + 64;
    float*  esum  = ws + 64064;
    float*  diag  = ws + 72064;
    __bf16* xb    = (__bf16*)(ws + 80064);
    __bf16* cclsb = (__bf16*)(ws + 342208);
    __bf16* Pt    = (__bf16*)(ws + 604352);
    __bf16* simb  = (__bf16*)(ws + 2652352);
    // total 6,748,352 floats = 27.0 MiB

    float* padf = (float*)cclsb + 256000;     // ccls rows 1000..1023 as f32

    k_pre<<<856, 256, 0, stream>>>(x, proxies, xb, ssqp, esum, padf, acc);
    k_tpose<<<dim3(125, 8), 256, 0, stream>>>(proxies, ssqp, Pt, cclsb);

    k_gemms<<<512, 256, 0, stream>>>(xb, Pt, cclsb, simb, esum, diag);

    k_rowloss<<<PB, 256, 0, stream>>>(simb, target, acc);
    k_final<<<1, 256, 0, stream>>>(esum, diag, acc, out);
}

// Round 14
// 140.470 us; speedup vs baseline: 1.0042x; 1.0042x over previous
//
#include <hip/hip_runtime.h>
#include <hip/hip_bf16.h>
#include <math.h>

// ProxyGML: B=1024, DIM=512, C=1000, N=8
#define PB   1024
#define PDIM 512
#define PC   1000
#define PN   8
#define PCN  8000
#define PTOPK 400
#define NONPOS_K 392
#define NBIN 1024
#define CANDMAX 1024

typedef __bf16 bf16x8 __attribute__((ext_vector_type(8)));
typedef __bf16 bf16x4 __attribute__((ext_vector_type(4)));
typedef float  f32x4  __attribute__((ext_vector_type(4)));

__device__ static inline void async_load16(const __bf16* g, __bf16* l) {
    __builtin_amdgcn_global_load_lds(
        (const __attribute__((address_space(1))) void*)g,
        (__attribute__((address_space(3))) void*)l,
        16, 0, 0);
}

// ----------------------------------------------------------------- pre ----
// b<512: x->bf16. 512..767: P column-ssq partials. 768+: zero esum/diag and
// ccls pad rows (classes 1000..1023).
__global__ __launch_bounds__(256) void k_pre(const float* __restrict__ x,
                                             const float* __restrict__ P,
                                             __bf16* __restrict__ xb,
                                             float* __restrict__ ssqp,
                                             float* __restrict__ esd,
                                             float* __restrict__ padf,
                                             float* __restrict__ acc) {
    int b = blockIdx.x, tid = threadIdx.x;
    if (b == 0 && tid < 8) acc[tid] = 0.f;
    if (b < 512) {
        int i = b * 256 + tid;
        float4 v = ((const float4*)x)[i];
        bf16x4 o;
        o[0] = (__bf16)v.x; o[1] = (__bf16)v.y; o[2] = (__bf16)v.z; o[3] = (__bf16)v.w;
        ((bf16x4*)xb)[i] = o;
    } else if (b < 768) {
        int idx = b - 512;              // 0..255
        int slice = idx & 7, jb = idx >> 3;
        int j = jb * 256 + tid;
        if (j < PCN) {
            const float* p = P + (size_t)(slice * 64) * PCN + j;
            float ss = 0.f;
#pragma unroll 8
            for (int r = 0; r < 64; ++r) {
                float v = p[(size_t)r * PCN];
                ss = fmaf(v, v, ss);
            }
            ssqp[slice * PCN + j] = ss;
        }
    } else {
        int i = (b - 768) * 256 + tid;  // 0..22271
        if (i < 16000) esd[i] = 0.f;
        else if (i < 16000 + 6144) padf[i - 16000] = 0.f;  // 24x512 bf16 pad
    }
}

// ---------------- P (512x8000) -> Pt bf16 (8000x512) + fused ccls ---------
__global__ __launch_bounds__(256) void k_tpose(const float* __restrict__ P,
                                               const float* __restrict__ ssqp,
                                               __bf16* __restrict__ Pt,
                                               __bf16* __restrict__ ccls) {
    __shared__ float t[64][65];
    __shared__ float sinv[64];
    int tid = threadIdx.x;
    int tx = tid & 63, ty = tid >> 6;
    int j0 = blockIdx.x * 64, d0 = blockIdx.y * 64;
    if (tid < 64) {
        float sq = 0.f;
#pragma unroll
        for (int p2 = 0; p2 < 8; ++p2) sq += ssqp[p2 * PCN + j0 + tid];
        sinv[tid] = 1.0f / fmaxf(sqrtf(sq), 1e-12f);
    }
#pragma unroll
    for (int r = 0; r < 16; ++r) {
        int d = d0 + ty * 16 + r;
        t[ty * 16 + r][tx] = P[(size_t)d * PCN + j0 + tx];
    }
    __syncthreads();
    float cs0 = 0.f, cs1 = 0.f;
#pragma unroll
    for (int r = 0; r < 16; ++r) {
        int jl = ty * 16 + r;
        float val = t[tx][jl] * sinv[jl];
        Pt[(size_t)(j0 + jl) * PDIM + d0 + tx] = (__bf16)val;
        if (r < 8) cs0 += val; else cs1 += val;
    }
    int c0 = (j0 >> 3) + ty * 2;           // 16 j's = 2 whole classes
    ccls[(size_t)c0 * PDIM + d0 + tx] = (__bf16)cs0;
    ccls[(size_t)(c0 + 1) * PDIM + d0 + tx] = (__bf16)cs1;
}

// -------------- pair-fused GEMM: block (jt,t) shares the Pt tile ----------
// sim[m=t-tile][j=jt-tile] = xb · Pt^T   and
// clog[j=jt-tile][c=t-tile] = Pt · ccls^T -> esum/diag epilogue.
// 3 tiles staged per K-step, 32 MFMA per barrier.
__global__ __launch_bounds__(256, 2) void k_gemms(const __bf16* __restrict__ xb,
                                                  const __bf16* __restrict__ Pt,
                                                  const __bf16* __restrict__ ccls,
                                                  __bf16* __restrict__ simb,
                                                  float* __restrict__ esum,
                                                  float* __restrict__ diag) {
    __shared__ __bf16 Xs[2][128 * 32];
    __shared__ __bf16 Ps[2][128 * 32];
    __shared__ __bf16 Cs[2][128 * 32];
    int tid = threadIdx.x;
    int w = tid >> 6, lane = tid & 63;
    int wr = w >> 1, wc = w & 1;
    int quad = lane >> 4, l15 = lane & 15;
    int id = blockIdx.x;
    int jt = id >> 3, t = id & 7;          // 63 x 8
    int m0 = t * 128;                      // xb rows / ccls rows (exact)
    int n0 = jt * 128;                     // Pt rows (guard 8000)

    f32x4 accS[4][4] = {};                 // sim
    f32x4 accC[4][4] = {};                 // clog

#define STAGE3(buf, k0) {                                                     \
    _Pragma("unroll")                                                         \
    for (int pass = 0; pass < 2; ++pass) {                                    \
        int cc_ = pass * 256 + w * 64 + lane;                                 \
        int row_ = cc_ >> 2, ko_ = (cc_ & 3) * 8;                             \
        async_load16(xb + (size_t)(m0 + row_) * PDIM + (k0) + ko_,            \
                     &Xs[buf][cc_ * 8]);                                      \
        int prow = n0 + row_; if (prow > PCN - 1) prow = PCN - 1;             \
        async_load16(Pt + (size_t)prow * PDIM + (k0) + ko_,                   \
                     &Ps[buf][cc_ * 8]);                                      \
        async_load16(ccls + (size_t)(m0 + row_) * PDIM + (k0) + ko_,          \
                     &Cs[buf][cc_ * 8]);                                      \
    } }

    STAGE3(0, 0)
    for (int it = 0; it < 16; ++it) {
        int cur = it & 1;
        __syncthreads();
        if (it < 15) STAGE3(cur ^ 1, (it + 1) * 32)
        bf16x8 xa[4], pb[4], pa[4], cb[4];
#pragma unroll
        for (int i = 0; i < 4; ++i) {
            xa[i] = *(const bf16x8*)&Xs[cur][(wr * 64 + i * 16 + l15) * 32 + quad * 8];
            pb[i] = *(const bf16x8*)&Ps[cur][(wc * 64 + i * 16 + l15) * 32 + quad * 8];
            pa[i] = *(const bf16x8*)&Ps[cur][(wr * 64 + i * 16 + l15) * 32 + quad * 8];
            cb[i] = *(const bf16x8*)&Cs[cur][(wc * 64 + i * 16 + l15) * 32 + quad * 8];
        }
#pragma unroll
        for (int i = 0; i < 4; ++i)
#pragma unroll
            for (int j = 0; j < 4; ++j) {
                accS[i][j] = __builtin_amdgcn_mfma_f32_16x16x32_bf16(
                    xa[i], pb[j], accS[i][j], 0, 0, 0);
                accC[i][j] = __builtin_amdgcn_mfma_f32_16x16x32_bf16(
                    pa[i], cb[j], accC[i][j], 0, 0, 0);
            }
    }
#undef STAGE3

    // epilogue 1: sim store (rows m0+.., cols n0+.. over CN)
#pragma unroll
    for (int i = 0; i < 4; ++i) {
        int r0 = m0 + wr * 64 + i * 16 + quad * 4;
#pragma unroll
        for (int j = 0; j < 4; ++j) {
            int cc = n0 + wc * 64 + j * 16 + l15;
            if (cc < PCN) {
#pragma unroll
                for (int r = 0; r < 4; ++r)
                    simb[(size_t)(r0 + r) * PCN + cc] = (__bf16)accS[i][j][r];
            }
        }
    }
    // epilogue 2: clog -> esum/diag (rows n0+.. over CN, cols m0+.. over C)
#pragma unroll
    for (int i = 0; i < 4; ++i) {
        int r0 = n0 + wr * 64 + i * 16 + quad * 4;
        float psum[4] = {0.f, 0.f, 0.f, 0.f};
#pragma unroll
        for (int j = 0; j < 4; ++j) {
            int cc = m0 + wc * 64 + j * 16 + l15;
            bool cvalid = (cc < PC);
#pragma unroll
            for (int r = 0; r < 4; ++r) {
                float v = accC[i][j][r];
                psum[r] += cvalid ? expf(v) : 0.f;
                int rr = r0 + r;
                if (cvalid && rr < PCN && cc == (rr >> 3)) diag[rr] = v;
            }
        }
#pragma unroll
        for (int off = 1; off < 16; off <<= 1)
#pragma unroll
            for (int r = 0; r < 4; ++r)
                psum[r] += __shfl_xor(psum[r], off, 64);
        if (l15 == 0) {
#pragma unroll
            for (int r = 0; r < 4; ++r) {
                int rr = r0 + r;
                if (rr < PCN) atomicAdd(&esum[rr], psum[r]);
            }
        }
    }
}

// ------------------------------------------------------------- row loss ---
// Register-resident bf16 row; 1024-bin histogram select for tau; ties
// resolved by index order via parallel class-order prefix scan.
__global__ __launch_bounds__(256) void k_rowloss(const __bf16* __restrict__ sim,
                                                 const int* __restrict__ target,
                                                 float* __restrict__ acc) {
    __shared__ unsigned hist[NBIN];
    __shared__ float redf[8];
    __shared__ unsigned wtot[4];
    __shared__ float cand[CANDMAX];
    __shared__ unsigned candn;
    __shared__ int s_bin, s_A;
    __shared__ float s_tau;
    __shared__ int s_gt, s_eq;
    __shared__ float s_et;

    int b = blockIdx.x, tid = threadIdx.x;
    int lane = tid & 63, wv = tid >> 6;
    const bf16x8* row8 = (const bf16x8*)(sim + (size_t)b * PCN);
    int targ = target[b];

#pragma unroll
    for (int k = 0; k < 4; ++k) hist[tid + 256 * k] = 0u;
    if (tid == 0) candn = 0u;

    float pv[4][8];
    float lmn = INFINITY, lmx = -INFINITY;
#pragma unroll
    for (int k = 0; k < 4; ++k) {
        int c = tid + 256 * k;
        if (c < PC) {
            bf16x8 vv = row8[c];
#pragma unroll
            for (int n = 0; n < 8; ++n) pv[k][n] = (float)vv[n];
            if (c != targ) {
#pragma unroll
                for (int n = 0; n < 8; ++n) {
                    lmn = fminf(lmn, pv[k][n]);
                    lmx = fmaxf(lmx, pv[k][n]);
                }
            }
        } else {
#pragma unroll
            for (int n = 0; n < 8; ++n) pv[k][n] = 0.f;
        }
    }
    for (int off = 32; off; off >>= 1) {
        lmn = fminf(lmn, __shfl_down(lmn, off, 64));
        lmx = fmaxf(lmx, __shfl_down(lmx, off, 64));
    }
    if (lane == 0) { redf[wv] = lmn; redf[4 + wv] = lmx; }
    __syncthreads();
    float lo = fminf(fminf(redf[0], redf[1]), fminf(redf[2], redf[3]));
    float hi = fmaxf(fmaxf(redf[4], redf[5]), fmaxf(redf[6], redf[7]));
    float range = hi - lo;
    float scale = (range > 0.f) ? (float)NBIN / range : 0.f;

#pragma unroll
    for (int k = 0; k < 4; ++k) {
        int c = tid + 256 * k;
        if (c < PC && c != targ) {
#pragma unroll
            for (int n = 0; n < 8; ++n) {
                int bin = (int)((pv[k][n] - lo) * scale);
                bin = bin < 0 ? 0 : (bin > NBIN - 1 ? NBIN - 1 : bin);
                atomicAdd(&hist[bin], 1u);
            }
        }
    }
    __syncthreads();

    // suffix scan over 1024 bins
    int b0 = tid * 4;
    unsigned h0 = hist[b0], h1 = hist[b0 + 1], h2 = hist[b0 + 2], h3 = hist[b0 + 3];
    unsigned l3 = h3, l2 = h2 + l3, l1 = h1 + l2, l0 = h0 + l1;
    unsigned T = l0;
#pragma unroll
    for (int step = 1; step < 64; step <<= 1) {
        unsigned u = __shfl_down(T, step, 64);
        if (lane + step < 64) T += u;
    }
    if (lane == 0) wtot[wv] = T;
    __syncthreads();
    unsigned tail = 0;
#pragma unroll
    for (int w2 = 0; w2 < 4; ++w2) if (w2 > wv) tail += wtot[w2];
    unsigned E = T - l0 + tail;
    {
        unsigned sfx[4] = {l0 + E, l1 + E, l2 + E, l3 + E};
        unsigned nxt[4] = {l1 + E, l2 + E, l3 + E, E};
#pragma unroll
        for (int i = 0; i < 4; ++i)
            if (sfx[i] >= NONPOS_K && nxt[i] < NONPOS_K) {
                s_bin = b0 + i;
                s_A = (int)nxt[i];
            }
    }
    __syncthreads();
    int tbin = s_bin, A = s_A;

    // collect candidates in tau's bin
#pragma unroll
    for (int k = 0; k < 4; ++k) {
        int c = tid + 256 * k;
        if (c < PC && c != targ) {
#pragma unroll
            for (int n = 0; n < 8; ++n) {
                int bin = (int)((pv[k][n] - lo) * scale);
                bin = bin < 0 ? 0 : (bin > NBIN - 1 ? NBIN - 1 : bin);
                if (bin == tbin) {
                    unsigned idx = atomicAdd(&candn, 1u);
                    if (idx < CANDMAX) cand[idx] = pv[k][n];
                }
            }
        }
    }
    __syncthreads();
    int m = (int)candn; if (m > CANDMAX) m = CANDMAX;
    int rank = NONPOS_K - A;
    for (int ci = tid; ci < m; ci += 256) {
        float val = cand[ci];
        int g = 0, e = 0;
        for (int i = 0; i < m; ++i) {
            g += cand[i] > val;
            e += cand[i] == val;
        }
        if (g < rank && rank <= g + e) { s_tau = val; s_gt = g; s_eq = e; }
    }
    __syncthreads();
    float tau = s_tau;
    int cgt = A + s_gt, ceq = s_eq;
    int rem = NONPOS_K - cgt;              // ties to include, by index order
    bool all_eq = (rem >= ceq);

    // parallel tie offsets in class-index order
    int offs[4] = {0, 0, 0, 0};
    if (!all_eq) {
        unsigned chunk_base = 0;
#pragma unroll
        for (int k = 0; k < 4; ++k) {
            int c = tid + 256 * k;
            unsigned tn = 0;
            if (c < PC && c != targ) {
#pragma unroll
                for (int n = 0; n < 8; ++n) tn += (pv[k][n] == tau) ? 1u : 0u;
            }
            unsigned inc = tn;                       // inclusive wave scan
#pragma unroll
            for (int step = 1; step < 64; step <<= 1) {
                unsigned u = __shfl_up(inc, step, 64);
                if (lane >= step) inc += u;
            }
            __syncthreads();
            if (lane == 63) wtot[wv] = inc;
            __syncthreads();
            unsigned base = 0;
#pragma unroll
            for (int w2 = 0; w2 < 4; ++w2) if (w2 < wv) base += wtot[w2];
            offs[k] = (int)(chunk_base + base + inc - tn);
            chunk_base += wtot[0] + wtot[1] + wtot[2] + wtot[3];
        }
    }

    // logits -> exp -> loss
    float psum = 0.f;
#pragma unroll
    for (int k = 0; k < 4; ++k) {
        int c = tid + 256 * k;
        if (c >= PC) continue;
        float lg = 0.f;
        if (c == targ) {
#pragma unroll
            for (int n = 0; n < 8; ++n) lg += pv[k][n];
        } else {
#pragma unroll
            for (int n = 0; n < 8; ++n) {
                float v = pv[k][n];
                bool sel = v > tau;
                if (!sel && v == tau) {
                    if (all_eq) sel = true;
                    else { sel = (offs[k] < rem); offs[k]++; }
                }
                if (sel) lg += v;
            }
        }
        float e = (lg != 0.0f) ? expf(lg) : 0.0f;
        psum += e;
        if (c == targ) s_et = e;
    }
    for (int off = 32; off; off >>= 1) psum += __shfl_down(psum, off, 64);
    if (lane == 0) redf[wv] = psum;
    __syncthreads();
    if (tid == 0) {
        float denom = 1e-8f + redf[0] + redf[1] + redf[2] + redf[3];
        atomicAdd(acc, -logf(s_et / denom + 1e-20f));
    }
}

// --------------------------------------------------------------- final ----
__global__ __launch_bounds__(256) void k_final(const float* __restrict__ esum,
                                               const float* __restrict__ diag,
                                               const float* __restrict__ acc,
                                               float* __restrict__ out) {
    __shared__ float redf[4];
    int tid = threadIdx.x, lane = tid & 63, wv = tid >> 6;
    float s = 0.f;
    for (int j = tid; j < PCN; j += 256)
        s += logf(esum[j]) - diag[j];
    for (int off = 32; off; off >>= 1) s += __shfl_down(s, off, 64);
    if (lane == 0) redf[wv] = s;
    __syncthreads();
    if (tid == 0) {
        float rg = (redf[0] + redf[1] + redf[2] + redf[3]) * (1.0f / PCN);
        float lc = acc[0] * (1.0f / PB);
        out[0] = lc + 0.3f * rg;
        out[1] = lc;
    }
}

// ---------------------------------------------------------------------------
extern "C" void kernel_launch(void* const* d_in, const int* in_sizes, int n_in,
                              void* d_out, int out_size, void* d_ws, size_t ws_size,
                              hipStream_t stream) {
    const float* x       = (const float*)d_in[0];   // (1024, 512)
    const float* proxies = (const float*)d_in[1];   // (512, 8000)
    const int*   target  = (const int*)d_in[2];     // (1024,)
    float* out = (float*)d_out;
    float* ws  = (float*)d_ws;

    // workspace layout (float offsets) — spans verified:
    //   acc    [0,      64)
    //   ssqp   [64,     64064)     8x8000 f32
    //   esum   [64064,  72064)     8000 f32
    //   diag   [72064,  80064)     8000 f32
    //   xb     [80064,  342208)    1024x512 bf16 = 262144 f32
    //   cclsb  [342208, 604352)    1024x512 bf16 = 262144 f32
    //   Pt     [604352, 2652352)   8000x512 bf16 = 2048000 f32
    //   simb   [2652352,6748352)   1024x8000 bf16 = 4096000 f32
    float*  acc   = ws;
    float*  ssqp  = ws + 64;
    float*  esum  = ws + 64064;
    float*  diag  = ws + 72064;
    __bf16* xb    = (__bf16*)(ws + 80064);
    __bf16* cclsb = (__bf16*)(ws + 342208);
    __bf16* Pt    = (__bf16*)(ws + 604352);
    __bf16* simb  = (__bf16*)(ws + 2652352);
    // total 6,748,352 floats = 27.0 MiB

    float* padf = (float*)cclsb + 256000;     // ccls rows 1000..1023 as f32

    k_pre<<<856, 256, 0, stream>>>(x, proxies, xb, ssqp, esum, padf, acc);
    k_tpose<<<dim3(125, 8), 256, 0, stream>>>(proxies, ssqp, Pt, cclsb);

    k_gemms<<<504, 256, 0, stream>>>(xb, Pt, cclsb, simb, esum, diag);

    k_rowloss<<<PB, 256, 0, stream>>>(simb, target, acc);
    k_final<<<1, 256, 0, stream>>>(esum, diag, acc, out);
}